// Round 12
// baseline (879.734 us; speedup 1.0000x reference)
//
#include <hip/hip_runtime.h>
#include <hip/hip_bf16.h>
#include <cstdint>

#define NB    16384
#define DIMX  2048
#define STATE 2048
#define SELH  1024

typedef unsigned short u16;
typedef short  short8_t __attribute__((ext_vector_type(8)));
typedef float  f32x16   __attribute__((ext_vector_type(16)));

__device__ __forceinline__ u16 f2bf(float f) {
  unsigned u = __builtin_bit_cast(unsigned, f);
  u += 0x7fffu + ((u >> 16) & 1u);   // RNE
  return (u16)(u >> 16);
}
__device__ __forceinline__ float bf2f(u16 h) {
  unsigned u = ((unsigned)h) << 16;
  return __builtin_bit_cast(float, u);
}
__device__ __forceinline__ float sigmoidf_(float x) { return 1.f / (1.f + __expf(-x)); }
__device__ __forceinline__ float tanhf_(float x)    { return 2.f / (1.f + __expf(-2.f * x)) - 1.f; }

__device__ __forceinline__ f32x16 mfma32(short8_t a, short8_t b, f32x16 c) {
  return __builtin_amdgcn_mfma_f32_32x32x16_bf16(a, b, c, 0, 0, 0);
}

// ---- async global->LDS, 16B per lane ----
__device__ __forceinline__ void gload16(const void* g, const void* l) {
  __builtin_amdgcn_global_load_lds(
      (const __attribute__((address_space(1))) unsigned int*)(uintptr_t)g,
      (__attribute__((address_space(3))) unsigned int*)(unsigned int)(uintptr_t)l,
      16, 0, 0);
}

// aligned LDS vector read (ensure ds_read_b128)
#define LDS_V(p) (*(const short8_t*)__builtin_assume_aligned((const void*)(p), 16))

// ---- f32 -> bf16 convert, vectorized ----
__global__ __launch_bounds__(256) void k_f32_to_bf16(const float* __restrict__ src,
                                                     u16* __restrict__ dst, int n4) {
  int i = blockIdx.x * blockDim.x + threadIdx.x;
  int stride = gridDim.x * blockDim.x;
  for (; i < n4; i += stride) {
    float4 v = ((const float4*)src)[i];
    ushort4 o;
    o.x = f2bf(v.x); o.y = f2bf(v.y); o.z = f2bf(v.z); o.w = f2bf(v.w);
    ((ushort4*)dst)[i] = o;
  }
}

// =====================================================================
// 256x256 GEMM on mfma_f32_32x32x16_bf16. 512 thr = 8 waves (2Mr x 4Nc),
// per-wave 128x64 = 4mf(32) x 2nf(32), BK=64 (4 kk of 16).
// LDS 128 KiB: A buf D at D*32768: [256 rows][64 k] 128B rows;
//              B at 65536 + D*32768: same shape ([256 n-rows][64 k]).
// Bank swizzle (both): byte = (kk*32 + (l>>5)*16) ^ ((row&7)<<4) ->
// conflict-free b128 (8-cycle minimum). Staging: linear gload_lds dest,
// source k-slot = ((tid&7) ^ ((tid>>3)&7))*8 (inverse swizzle).
// Schedule: ONE barrier per K-tile:
//   {lgkmcnt(0) [free]; vmcnt(0) [cold: staged a full tile ago]; s_barrier;
//    sched_barrier; stage T+1 (8 gloads -> D^1); 4x{6 ds_read; 8 MFMA}}
// Frag maps: A/B lane l -> (row l&31, k (l>>5)*8+j)  [analog of verified
// 16x16x32]; C/D col=l&31, row=(reg&3)+8*(reg>>2)+4*(l>>5) [m74/m101].
// EPI: 0 bf16 | 1 silu->bf16 | 2 f32
//      3 fused gate. B-row map r -> ((r>>5)&3)*STATE + bx*64 + (r>>7)*32
//        + (r&31): wave wc's col-tiles ct=2wc+nf are quad ct&3 of state
//        block t=ct>>2 -> wc even holds (a,b), wc odd (c,d) of same cols.
//        Even: h = sig(a)*hp + tanh(b)*u -> gmem + LDS stash; sync;
//        Odd:  y = tanh(c)*h + d*sig(dd)*u -> bf16.
// =====================================================================
template <int EPI, int KD, int NCOLS>
__global__ __launch_bounds__(512, 2) void k_gemm256(const u16* __restrict__ A,
                                                    const u16* __restrict__ Bsrc,
                                                    float* __restrict__ f32out,
                                                    u16* __restrict__ bfout,
                                                    const float* __restrict__ hprev,
                                                    const u16* __restrict__ ubf,
                                                    const float* __restrict__ dvec) {
  __shared__ __align__(16) char smem[131072];
  const int tid = threadIdx.x;
  const int w = tid >> 6, l = tid & 63;
  const int wr = w >> 2, wc = w & 3;
  const int bx = blockIdx.x, by = blockIdx.y;
  const int m0 = by * 256;

  // ---- ds_read bases ----
  const unsigned x0 = (unsigned)(((l >> 5) * 16) ^ ((l & 7) << 4));
  const unsigned kx[4] = {x0, x0 ^ 32u, x0 ^ 64u, x0 ^ 96u};
  const unsigned aRowB = (unsigned)(wr * 16384 + (l & 31) * 128);
  const unsigned bRowB = (unsigned)(wc * 8192 + (l & 31) * 128);

  // ---- staging sources (inverse-swizzled) ----
  const int rT = tid >> 3;                         // row within 64-row gload block
  const int kT = ((tid & 7) ^ (rT & 7)) * 8;       // k-elem offset
  const u16* aSrc = A + (size_t)(m0 + rT) * KD + kT;
  const u16* bSrcP[4];
#pragma unroll
  for (int g = 0; g < 4; ++g) {
    const int r = g * 64 + rT;
    size_t wrow;
    if constexpr (EPI <= 2) {
      wrow = (size_t)bx * 256 + r;
    } else {
      wrow = (size_t)((r >> 5) & 3) * STATE + bx * 64 + (r >> 7) * 32 + (r & 31);
    }
    bSrcP[g] = Bsrc + wrow * KD + kT;
  }

  auto stageAll = [&](int k0n, unsigned Dd) {
#pragma unroll
    for (int g = 0; g < 4; ++g)
      gload16(aSrc + (size_t)g * 64 * KD + k0n,
              smem + Dd * 32768u + g * 8192u + (unsigned)tid * 16u);
#pragma unroll
    for (int g = 0; g < 4; ++g)
      gload16(bSrcP[g] + k0n,
              smem + 65536u + Dd * 32768u + g * 8192u + (unsigned)tid * 16u);
  };

  f32x16 acc[4][2];
#pragma unroll
  for (int i = 0; i < 4; ++i)
#pragma unroll
    for (int j = 0; j < 2; ++j)
#pragma unroll
      for (int r = 0; r < 16; ++r) acc[i][j][r] = 0.f;

#define KTILE(D, DO_STAGE, K0N)                                                \
  {                                                                            \
    asm volatile("s_waitcnt lgkmcnt(0)" ::: "memory");                         \
    asm volatile("s_waitcnt vmcnt(0)" ::: "memory");                           \
    __builtin_amdgcn_s_barrier();                                              \
    __builtin_amdgcn_sched_barrier(0);                                         \
    if (DO_STAGE) stageAll((K0N), (D) ^ 1u);                                   \
    _Pragma("unroll") for (int kk = 0; kk < 4; ++kk) {                         \
      short8_t af[4], bf[2];                                                   \
      _Pragma("unroll") for (int mf = 0; mf < 4; ++mf)                         \
          af[mf] = LDS_V(smem + (D) * 32768u + aRowB + mf * 4096u + kx[kk]);   \
      _Pragma("unroll") for (int nf = 0; nf < 2; ++nf)                         \
          bf[nf] = LDS_V(smem + 65536u + (D) * 32768u + bRowB + nf * 4096u +   \
                         kx[kk]);                                              \
      __builtin_amdgcn_s_setprio(1);                                           \
      _Pragma("unroll") for (int mf = 0; mf < 4; ++mf)                         \
        _Pragma("unroll") for (int nf = 0; nf < 2; ++nf)                       \
            acc[mf][nf] = mfma32(af[mf], bf[nf], acc[mf][nf]);                 \
      __builtin_amdgcn_s_setprio(0);                                           \
    }                                                                          \
  }

  // prologue: stage T0 into buf0; first KTILE's vmcnt(0)+barrier publishes it
  stageAll(0, 0u);

  constexpr int NT = KD / 64;   // 16 or 32 (even)
#pragma unroll 1
  for (int T = 0; T < NT; T += 2) {
    KTILE(0u, (T + 1 < NT), (T + 1) * 64);
    KTILE(1u, (T + 2 < NT), (T + 2) * 64);
  }
#undef KTILE

  // ---- epilogue ----
  if constexpr (EPI <= 2) {
#pragma unroll
    for (int mf = 0; mf < 4; ++mf)
#pragma unroll
      for (int nf = 0; nf < 2; ++nf)
#pragma unroll
        for (int reg = 0; reg < 16; ++reg) {
          const int row = m0 + wr * 128 + mf * 32 +
                          (reg & 3) + 8 * (reg >> 2) + 4 * (l >> 5);
          const int col = bx * 256 + wc * 64 + nf * 32 + (l & 31);
          const size_t idx = (size_t)row * NCOLS + col;
          const float v = acc[mf][nf][reg];
          if constexpr (EPI == 0) {
            bfout[idx] = f2bf(v);
          } else if constexpr (EPI == 1) {
            bfout[idx] = f2bf(v * sigmoidf_(v));
          } else {
            f32out[idx] = v;
          }
        }
  } else {
    const int t = wc >> 1;
    const bool evenw = (wc & 1) == 0;
    const int s = bx * 64 + t * 32 + (l & 31);
    float* hstash = (float*)smem;                 // [wr*2+t][128][33] f32
    const int stashBase = (wr * 2 + t) * 128 * 33;
    __syncthreads();                              // K-loop LDS fully retired
    if (evenw) {
#pragma unroll
      for (int mf = 0; mf < 4; ++mf)
#pragma unroll
        for (int reg = 0; reg < 16; ++reg) {
          const int lrow = mf * 32 + (reg & 3) + 8 * (reg >> 2) + 4 * (l >> 5);
          const int row = m0 + wr * 128 + lrow;
          const size_t idx = (size_t)row * STATE + s;
          const float a = acc[mf][0][reg];
          const float b = acc[mf][1][reg];
          const float uu = bf2f(ubf[idx]);
          const float hp = hprev[idx];
          const float h = sigmoidf_(a) * hp + tanhf_(b) * uu;
          f32out[idx] = h;                        // h_t
          hstash[stashBase + lrow * 33 + (l & 31)] = h;
        }
    }
    __syncthreads();
    if (!evenw) {
      const float dval = dvec[s];
#pragma unroll
      for (int mf = 0; mf < 4; ++mf)
#pragma unroll
        for (int reg = 0; reg < 16; ++reg) {
          const int lrow = mf * 32 + (reg & 3) + 8 * (reg >> 2) + 4 * (l >> 5);
          const int row = m0 + wr * 128 + lrow;
          const size_t idx = (size_t)row * STATE + s;
          const float c = acc[mf][0][reg];
          const float dd = acc[mf][1][reg];
          const float uu = bf2f(ubf[idx]);
          const float h = hstash[stashBase + lrow * 33 + (l & 31)];
          bfout[idx] = f2bf(tanhf_(c) * h + dval * sigmoidf_(dd) * uu);  // y
        }
    }
  }
}

extern "C" void kernel_launch(void* const* d_in, const int* in_sizes, int n_in,
                              void* d_out, int out_size, void* d_ws, size_t ws_size,
                              hipStream_t stream) {
  const float* x   = (const float*)d_in[0];
  const float* h0  = (const float*)d_in[1];
  const float* Win = (const float*)d_in[2];
  const float* Wsi = (const float*)d_in[3];
  const float* Wso = (const float*)d_in[4];
  const float* Wou = (const float*)d_in[5];
  const float* dv  = (const float*)d_in[6];
  float* out  = (float*)d_out;
  float* hout = out + (size_t)NB * DIMX;   // second output: h_t

  u16* ws = (u16*)d_ws;
  size_t o = 0;
  u16* xb   = ws + o; o += (size_t)NB * DIMX;        // x bf16
  u16* ub   = ws + o; o += (size_t)NB * STATE;       // u bf16
  u16* yb   = ws + o; o += (size_t)NB * STATE;       // y bf16
  u16* sh   = ws + o; o += (size_t)NB * SELH;        // sel_h bf16
  u16* wib  = ws + o; o += (size_t)STATE * DIMX;     // W_in bf16
  u16* wsib = ws + o; o += (size_t)SELH * DIMX;      // W_sel_in bf16
  u16* wsob = ws + o; o += (size_t)4 * STATE * SELH; // W_sel_out bf16
  u16* wob  = ws + o; o += (size_t)DIMX * STATE;     // W_out bf16

  k_f32_to_bf16<<<1024, 256, 0, stream>>>(x,   xb,   NB * DIMX / 4);
  k_f32_to_bf16<<<256,  256, 0, stream>>>(Win, wib,  STATE * DIMX / 4);
  k_f32_to_bf16<<<128,  256, 0, stream>>>(Wsi, wsib, SELH * DIMX / 4);
  k_f32_to_bf16<<<512,  256, 0, stream>>>(Wso, wsob, 4 * STATE * SELH / 4);
  k_f32_to_bf16<<<256,  256, 0, stream>>>(Wou, wob,  DIMX * STATE / 4);

  const dim3 blk(512);
  // u = x @ W_in^T
  k_gemm256<0, DIMX, STATE><<<dim3(STATE / 256, NB / 256), blk, 0, stream>>>(
      xb, wib, nullptr, ub, nullptr, nullptr, nullptr);
  // sel_h = silu(x @ W_sel_in^T)
  k_gemm256<1, DIMX, SELH><<<dim3(SELH / 256, NB / 256), blk, 0, stream>>>(
      xb, wsib, nullptr, sh, nullptr, nullptr, nullptr);
  // FUSED: all 4 quadrants of sel -> h_t (f32) AND y (bf16) in one pass
  k_gemm256<3, SELH, 0><<<dim3(STATE / 64, NB / 256), blk, 0, stream>>>(
      sh, wsob, hout, yb, h0, ub, dv);
  // out = y @ W_out^T
  k_gemm256<2, STATE, DIMX><<<dim3(DIMX / 256, NB / 256), blk, 0, stream>>>(
      yb, wob, out, nullptr, nullptr, nullptr, nullptr);
}